// Round 3
// baseline (329.885 us; speedup 1.0000x reference)
//
#include <hip/hip_runtime.h>
#include <stdint.h>

#define NOUT 1024
#define NIN  1024

// JAX Threefry-2x32-20, key=(0,42): ks0=0, ks1=42, ks2=0x1BD11BF0.
// Partitionable 32-bit bits: out0^out1 of block (hi=0, lo=flat_index).
// Bit-exact vs JAX verified R1-R6 (absmax 0.0).
// res = mu + ((Yb-mu)/sigma)*sigma + bias == Yb + bias (fp32 roundoff).
//
// Model (R6 confirmed): int wave64 VALU ~4.17 cyc/instr busy, VALUBusy 93%,
// 73 instr/elem vs ~71 floor. Remaining levers: 7% idle + loop overhead.
//
// R7: (a) drop the staging __syncthreads(): thread tid writes
//     s_fac[tid*4..tid*4+4), so wave sub writes exactly the quarter
//     [sub*256,(sub+1)*256) that it alone reads -- same-wave lgkmcnt
//     ordering suffices; each wave enters the main loop without waiting
//     for the other 3 waves' cold-start loads/sigmoids.
//     (b) unroll 4 (from 2) to halve per-iteration loop/address overhead.

__device__ __forceinline__ uint32_t rotl32(uint32_t x, uint32_t r) {
  return __builtin_rotateleft32(x, r);   // v_alignbit_b32
}

__global__ __launch_bounds__(256, 8) void syn_kernel(
    const float* __restrict__ input, const float* __restrict__ weight,
    const float* __restrict__ bias, const float* __restrict__ x0v,
    const float* __restrict__ dxv, const float* __restrict__ av,
    const float* __restrict__ dv, float* __restrict__ out) {
  const int bi = blockIdx.x;
  const int o  = bi >> 1;
  const int bh = bi & 1;            // batch half: b in [bh*64, bh*64+64)
  const int tid = threadIdx.x;
  __shared__ float s_fac[NIN];      // (d + a*sigmoid(dx*(w-x0))) * 2^23
  __shared__ uint32_t s_cnt[256];

  // Stage per-(o,i) synapse factor, pre-scaled by 2^23 so the Bernoulli test
  // is (float)(bits>>9) < in*fac23  ((bits>>9)*2^-23 exact; clip dropped:
  // fac=sigmoid(.) in (0,1), in in [0,1) -- verified R2/R3, absmax 0.0).
  // Wave-self-contained: wave sub stages exactly the s_fac quarter it reads,
  // so no block barrier is needed (same-wave ds ordering via lgkmcnt).
  {
    const int base = o * NIN + tid * 4;
    float4 w4  = *(const float4*)(weight + base);
    float4 x04 = *(const float4*)(x0v + base);
    float4 dx4 = *(const float4*)(dxv + base);
    float4 a4  = *(const float4*)(av + base);
    float4 d4  = *(const float4*)(dv + base);
    const float S = 8388608.0f;  // 2^23
    float s0 = (d4.x + a4.x / (1.0f + expf(-(dx4.x * (w4.x - x04.x))))) * S;
    float s1 = (d4.y + a4.y / (1.0f + expf(-(dx4.y * (w4.y - x04.y))))) * S;
    float s2 = (d4.z + a4.z / (1.0f + expf(-(dx4.z * (w4.z - x04.z))))) * S;
    float s3 = (d4.w + a4.w / (1.0f + expf(-(dx4.w * (w4.w - x04.w))))) * S;
    *(float4*)(s_fac + tid * 4) = make_float4(s0, s1, s2, s3);
  }
  // no __syncthreads() -- see comment above

  const int bl  = tid & 63;          // lane = batch row within half
  const int sub = tid >> 6;          // wave = i-quarter (0..3)
  const int b   = bh * 64 + bl;
  const uint32_t base_j = ((uint32_t)b << 20) | ((uint32_t)o << 10);
  const float* __restrict__ inrow = input + b * NIN;

  const uint32_t KS2 = 0x1BD11BF0u;  // uniform -> SGPR (VOP3-legal operand)

  uint32_t cnt0 = 0, cnt1 = 0;
  const int ic0 = sub * 256;

  // Prologue loads for iteration 0 (prefetch pipeline, depth 1).
  float4 inA = *(const float4*)(inrow + ic0);
  float4 inB = *(const float4*)(inrow + ic0 + 4);
  float4 sA  = *(const float4*)(s_fac + ic0);
  float4 sB  = *(const float4*)(s_fac + ic0 + 4);

  #pragma unroll 4
  for (int t = 0; t < 32; ++t) {
    const int ic  = ic0 + t * 8;
    const int icn = ic0 + ((t + 1) & 31) * 8;  // wraps on last iter (benign re-read)
    // Issue next iteration's loads now; the ~600-instr Threefry body below
    // hides the gather/LDS latency.
    float4 ninA = *(const float4*)(inrow + icn);
    float4 ninB = *(const float4*)(inrow + icn + 4);
    float4 nsA  = *(const float4*)(s_fac + icn);
    float4 nsB  = *(const float4*)(s_fac + icn + 4);

    uint32_t a[8], c[8];
    // Round 1 specialized: x0=0 initially -> a = j+42, c = rotl(a,13)^a.
    const uint32_t j42 = base_j + (uint32_t)(ic + 42);
    #pragma unroll
    for (int q = 0; q < 8; ++q) {
      uint32_t t0 = j42 + (uint32_t)q;
      a[q] = t0;
      c[q] = rotl32(t0, 13) ^ t0;
    }
    // Plain round: a += c; c = rotl(c,r) ^ a.
    #define RR(r) _Pragma("unroll") \
      for (int q=0;q<8;++q){ a[q]+=c[q]; c[q]=rotl32(c[q],(r)); c[q]^=a[q]; }
    // Fused round: previous injection's a-add folded in (v_add3_u32).
    #define RRF(r,ka) _Pragma("unroll") \
      for (int q=0;q<8;++q){ a[q]=a[q]+c[q]+(ka); c[q]=rotl32(c[q],(r)); c[q]^=a[q]; }
    // c-side injection only.
    #define INJC(kc) _Pragma("unroll") \
      for (int q=0;q<8;++q){ c[q]+=(kc); }
    RR(15) RR(26) RR(6)                 // r2-4
    INJC(0x1BD11BF1u)                   // inj1 c-side (ks2+1); a-side fused below
    RRF(17, 42u)                        // r5 with a += ks1(42)
    RR(29) RR(16) RR(24)                // r6-8
    INJC(2u)                            // inj2 c-side (ks0+2)
    RRF(13, KS2)                        // r9 with a += ks2
    RR(15) RR(26) RR(6)                 // r10-12
    INJC(45u)                           // inj3: a-side ks0=0, c-side ks1+3
    RR(17) RR(29) RR(16) RR(24)         // r13-16
    INJC(0x1BD11BF4u)                   // inj4 c-side (ks2+4)
    RRF(13, 42u)                        // r17 with a += ks1(42)
    RR(15) RR(26)                       // r18-19; r20 fused into TAIL
    #undef RR
    #undef RRF
    #undef INJC

    // Round 20 + inj5, xad-fused:
    //   a20 = a19+c19; r6 = rotl(c19,6);
    //   out1 = (r6 ^ a20) + 5  == c20 + 5   (LLVM matches (xor)+add -> v_xad_u32)
    //   bits = (a20 + KS2) ^ out1
    #define TAIL(Q, PV, CNT) { \
      uint32_t a20 = a[Q] + c[Q]; \
      uint32_t r6  = rotl32(c[Q], 6); \
      uint32_t o1  = (r6 ^ a20) + 5u; \
      uint32_t bits = (a20 + KS2) ^ o1; \
      float kf = (float)(bits >> 9);   /* exact: kf < 2^23 */ \
      CNT += (kf < (PV)); }
    TAIL(0, inA.x * sA.x, cnt0)
    TAIL(1, inA.y * sA.y, cnt0)
    TAIL(2, inA.z * sA.z, cnt0)
    TAIL(3, inA.w * sA.w, cnt0)
    TAIL(4, inB.x * sB.x, cnt1)
    TAIL(5, inB.y * sB.y, cnt1)
    TAIL(6, inB.z * sB.z, cnt1)
    TAIL(7, inB.w * sB.w, cnt1)
    #undef TAIL

    // Rotate prefetch registers.
    inA = ninA; inB = ninB; sA = nsA; sB = nsB;
  }

  s_cnt[tid] = cnt0 + cnt1;            // [sub][bl]
  __syncthreads();
  if (tid < 64) {
    uint32_t cc = s_cnt[tid] + s_cnt[64 + tid] + s_cnt[128 + tid] + s_cnt[192 + tid];
    out[(bh * 64 + tid) * NOUT + o] = (float)cc + bias[o];
  }
}

extern "C" void kernel_launch(void* const* d_in, const int* in_sizes, int n_in,
                              void* d_out, int out_size, void* d_ws, size_t ws_size,
                              hipStream_t stream) {
  const float* input  = (const float*)d_in[0];
  const float* weight = (const float*)d_in[1];
  const float* bias   = (const float*)d_in[2];
  const float* x0v    = (const float*)d_in[3];
  const float* dxv    = (const float*)d_in[4];
  const float* av     = (const float*)d_in[5];
  const float* dv     = (const float*)d_in[6];
  syn_kernel<<<2 * NOUT, 256, 0, stream>>>(input, weight, bias, x0v, dxv, av, dv,
                                           (float*)d_out);
}

// Round 4
// 320.416 us; speedup vs baseline: 1.0296x; 1.0296x over previous
//
#include <hip/hip_runtime.h>
#include <stdint.h>

#define NOUT 1024
#define NIN  1024

// JAX Threefry-2x32-20, key=(0,42): ks0=0, ks1=42, ks2=0x1BD11BF0.
// Partitionable 32-bit bits: out0^out1 of block (hi=0, lo=flat_index).
// Bit-exact vs JAX verified R1-R7 (absmax 0.0).
// res = mu + ((Yb-mu)/sigma)*sigma + bias == Yb + bias (fp32 roundoff).
//
// R8 = revert to R6 (best measured: 278.6 us kernel, VALUBusy 93.3%).
// R7's bundled changes (staging-barrier removal + unroll 4) both regressed:
// wave desync + I-cache pressure dropped VALUBusy to ~90%. Session pattern:
// all scheduling knobs (ILP-R2, occupancy-R3, barrier/unroll-R7) null or
// negative; only instruction-count cuts win (R4 77->74, R6 74->73).
// Model: 73 instr/elem x ~4.0-4.17 cyc/wave64-int-instr, 93% VALU busy;
// instr floor ~71; absolute floor ~249 us -> R6 at 89% of it.

__device__ __forceinline__ uint32_t rotl32(uint32_t x, uint32_t r) {
  return __builtin_rotateleft32(x, r);   // v_alignbit_b32
}

__global__ __launch_bounds__(256, 8) void syn_kernel(
    const float* __restrict__ input, const float* __restrict__ weight,
    const float* __restrict__ bias, const float* __restrict__ x0v,
    const float* __restrict__ dxv, const float* __restrict__ av,
    const float* __restrict__ dv, float* __restrict__ out) {
  const int bi = blockIdx.x;
  const int o  = bi >> 1;
  const int bh = bi & 1;            // batch half: b in [bh*64, bh*64+64)
  const int tid = threadIdx.x;
  __shared__ float s_fac[NIN];      // (d + a*sigmoid(dx*(w-x0))) * 2^23
  __shared__ uint32_t s_cnt[256];

  // Stage per-(o,i) synapse factor, pre-scaled by 2^23 so the Bernoulli test
  // is (float)(bits>>9) < in*fac23  ((bits>>9)*2^-23 exact; clip dropped:
  // fac=sigmoid(.) in (0,1), in in [0,1) -- verified R2/R3, absmax 0.0).
  {
    const int base = o * NIN + tid * 4;
    float4 w4  = *(const float4*)(weight + base);
    float4 x04 = *(const float4*)(x0v + base);
    float4 dx4 = *(const float4*)(dxv + base);
    float4 a4  = *(const float4*)(av + base);
    float4 d4  = *(const float4*)(dv + base);
    const float S = 8388608.0f;  // 2^23
    float s0 = (d4.x + a4.x / (1.0f + expf(-(dx4.x * (w4.x - x04.x))))) * S;
    float s1 = (d4.y + a4.y / (1.0f + expf(-(dx4.y * (w4.y - x04.y))))) * S;
    float s2 = (d4.z + a4.z / (1.0f + expf(-(dx4.z * (w4.z - x04.z))))) * S;
    float s3 = (d4.w + a4.w / (1.0f + expf(-(dx4.w * (w4.w - x04.w))))) * S;
    *(float4*)(s_fac + tid * 4) = make_float4(s0, s1, s2, s3);
  }
  __syncthreads();

  const int bl  = tid & 63;          // lane = batch row within half
  const int sub = tid >> 6;          // wave = i-quarter (0..3)
  const int b   = bh * 64 + bl;
  const uint32_t base_j = ((uint32_t)b << 20) | ((uint32_t)o << 10);
  const float* __restrict__ inrow = input + b * NIN;

  const uint32_t KS2 = 0x1BD11BF0u;  // uniform -> SGPR (VOP3-legal operand)

  uint32_t cnt0 = 0, cnt1 = 0;
  const int ic0 = sub * 256;

  // Prologue loads for iteration 0 (prefetch pipeline, depth 1).
  float4 inA = *(const float4*)(inrow + ic0);
  float4 inB = *(const float4*)(inrow + ic0 + 4);
  float4 sA  = *(const float4*)(s_fac + ic0);
  float4 sB  = *(const float4*)(s_fac + ic0 + 4);

  #pragma unroll 2
  for (int t = 0; t < 32; ++t) {
    const int ic  = ic0 + t * 8;
    const int icn = ic0 + ((t + 1) & 31) * 8;  // wraps on last iter (benign re-read)
    // Issue next iteration's loads now; the ~600-instr Threefry body below
    // hides the gather/LDS latency.
    float4 ninA = *(const float4*)(inrow + icn);
    float4 ninB = *(const float4*)(inrow + icn + 4);
    float4 nsA  = *(const float4*)(s_fac + icn);
    float4 nsB  = *(const float4*)(s_fac + icn + 4);

    uint32_t a[8], c[8];
    // Round 1 specialized: x0=0 initially -> a = j+42, c = rotl(a,13)^a.
    const uint32_t j42 = base_j + (uint32_t)(ic + 42);
    #pragma unroll
    for (int q = 0; q < 8; ++q) {
      uint32_t t0 = j42 + (uint32_t)q;
      a[q] = t0;
      c[q] = rotl32(t0, 13) ^ t0;
    }
    // Plain round: a += c; c = rotl(c,r) ^ a.
    #define RR(r) _Pragma("unroll") \
      for (int q=0;q<8;++q){ a[q]+=c[q]; c[q]=rotl32(c[q],(r)); c[q]^=a[q]; }
    // Fused round: previous injection's a-add folded in (v_add3_u32).
    #define RRF(r,ka) _Pragma("unroll") \
      for (int q=0;q<8;++q){ a[q]=a[q]+c[q]+(ka); c[q]=rotl32(c[q],(r)); c[q]^=a[q]; }
    // c-side injection only.
    #define INJC(kc) _Pragma("unroll") \
      for (int q=0;q<8;++q){ c[q]+=(kc); }
    RR(15) RR(26) RR(6)                 // r2-4
    INJC(0x1BD11BF1u)                   // inj1 c-side (ks2+1); a-side fused below
    RRF(17, 42u)                        // r5 with a += ks1(42)
    RR(29) RR(16) RR(24)                // r6-8
    INJC(2u)                            // inj2 c-side (ks0+2)
    RRF(13, KS2)                        // r9 with a += ks2
    RR(15) RR(26) RR(6)                 // r10-12
    INJC(45u)                           // inj3: a-side ks0=0, c-side ks1+3
    RR(17) RR(29) RR(16) RR(24)         // r13-16
    INJC(0x1BD11BF4u)                   // inj4 c-side (ks2+4)
    RRF(13, 42u)                        // r17 with a += ks1(42)
    RR(15) RR(26)                       // r18-19; r20 fused into TAIL
    #undef RR
    #undef RRF
    #undef INJC

    // Round 20 + inj5, xad-fused:
    //   a20 = a19+c19; r6 = rotl(c19,6);
    //   out1 = (r6 ^ a20) + 5  == c20 + 5   (LLVM matches (xor)+add -> v_xad_u32)
    //   bits = (a20 + KS2) ^ out1
    #define TAIL(Q, PV, CNT) { \
      uint32_t a20 = a[Q] + c[Q]; \
      uint32_t r6  = rotl32(c[Q], 6); \
      uint32_t o1  = (r6 ^ a20) + 5u; \
      uint32_t bits = (a20 + KS2) ^ o1; \
      float kf = (float)(bits >> 9);   /* exact: kf < 2^23 */ \
      CNT += (kf < (PV)); }
    TAIL(0, inA.x * sA.x, cnt0)
    TAIL(1, inA.y * sA.y, cnt0)
    TAIL(2, inA.z * sA.z, cnt0)
    TAIL(3, inA.w * sA.w, cnt0)
    TAIL(4, inB.x * sB.x, cnt1)
    TAIL(5, inB.y * sB.y, cnt1)
    TAIL(6, inB.z * sB.z, cnt1)
    TAIL(7, inB.w * sB.w, cnt1)
    #undef TAIL

    // Rotate prefetch registers.
    inA = ninA; inB = ninB; sA = nsA; sB = nsB;
  }

  s_cnt[tid] = cnt0 + cnt1;            // [sub][bl]
  __syncthreads();
  if (tid < 64) {
    uint32_t cc = s_cnt[tid] + s_cnt[64 + tid] + s_cnt[128 + tid] + s_cnt[192 + tid];
    out[(bh * 64 + tid) * NOUT + o] = (float)cc + bias[o];
  }
}

extern "C" void kernel_launch(void* const* d_in, const int* in_sizes, int n_in,
                              void* d_out, int out_size, void* d_ws, size_t ws_size,
                              hipStream_t stream) {
  const float* input  = (const float*)d_in[0];
  const float* weight = (const float*)d_in[1];
  const float* bias   = (const float*)d_in[2];
  const float* x0v    = (const float*)d_in[3];
  const float* dxv    = (const float*)d_in[4];
  const float* av     = (const float*)d_in[5];
  const float* dv     = (const float*)d_in[6];
  syn_kernel<<<2 * NOUT, 256, 0, stream>>>(input, weight, bias, x0v, dxv, av, dv,
                                           (float*)d_out);
}